// Round 8
// baseline (568.320 us; speedup 1.0000x reference)
//
#include <hip/hip_runtime.h>
#include <hip/hip_bf16.h>
#include <stdint.h>

typedef unsigned short u16;
typedef __attribute__((ext_vector_type(8))) short bf16x8;   // 8 bf16 = 4 VGPRs
typedef __attribute__((ext_vector_type(4))) short s16x4;    // 4 bf16 = 8B
typedef __attribute__((ext_vector_type(4))) float f32x4;

#define B_SZ 4
#define T_SZ 2048
#define C_SZ 1024
#define NH   16
#define HD   64
#define LOG2E 1.44269504088896340736f

__device__ __forceinline__ u16 f2bf(float f) {        // RNE
  unsigned int u = __float_as_uint(f);
  u += 0x7fffu + ((u >> 16) & 1u);
  return (u16)(u >> 16);
}
__device__ __forceinline__ u16 f2bf_hu(float f) {     // round-half-up (2 ops)
  return (u16)((__float_as_uint(f) + 0x8000u) >> 16);
}
__device__ __forceinline__ void gload_lds16(const u16* g, u16* l) {
  __builtin_amdgcn_global_load_lds((const __attribute__((address_space(1))) void*)g,
                                   (__attribute__((address_space(3))) void*)l, 16, 0, 0);
}

// fp32 -> bf16 cast, 8 elements/thread
__global__ void cast_f32_bf16(const float* __restrict__ in, u16* __restrict__ out, int n8) {
  int i = blockIdx.x * blockDim.x + threadIdx.x;
  if (i < n8) {
    const float4* p = (const float4*)in + (size_t)i * 2;
    float4 a = p[0], b = p[1];
    bf16x8 o;
    o[0] = (short)f2bf(a.x); o[1] = (short)f2bf(a.y);
    o[2] = (short)f2bf(a.z); o[3] = (short)f2bf(a.w);
    o[4] = (short)f2bf(b.x); o[5] = (short)f2bf(b.y);
    o[6] = (short)f2bf(b.z); o[7] = (short)f2bf(b.w);
    ((bf16x8*)out)[i] = o;
  }
}

// C[M,N] = A[M,K](bf16) * Bw[N,K](bf16)^T + bias[N](fp32).
// MODE 0: fp32 row-major out (O0).
// MODE 1: QKV head-split epilogue: O0=qh[B,H,T,64], O1=kh[B,H,T,64], O2=vth[B,H,64,T] (bf16).
// (256,3): cap VGPR at 170 (m97 K-loop fits in 164) -> 3 blocks/CU.
template <int MODE>
__launch_bounds__(256, 3)
__global__ void gemm_bt(const u16* __restrict__ A, const u16* __restrict__ Bw,
                        const float* __restrict__ bias,
                        void* __restrict__ O0, void* __restrict__ O1, void* __restrict__ O2,
                        int M, int N, int K) {
  __shared__ __align__(16) u16 As[128 * 32];
  __shared__ __align__(16) u16 Bs[128 * 32];
  const int tid = threadIdx.x;
  const int lane = tid & 63;
  const int w = tid >> 6;
  const int wr = w >> 1, wc = w & 1;
  const int quad = lane >> 4, l16 = lane & 15;
  const int m0 = blockIdx.y * 128;
  const int n0 = blockIdx.x * 128;

  const int srow = lane >> 2;
  const int scol = (lane & 3) * 8;
  const u16* gA = A + (size_t)(m0 + w * 32 + srow) * K + scol;
  const u16* gB = Bw + (size_t)(n0 + w * 32 + srow) * K + scol;
  u16* lA0 = &As[(w * 32) * 32];
  u16* lA1 = &As[(w * 32 + 16) * 32];
  u16* lB0 = &Bs[(w * 32) * 32];
  u16* lB1 = &Bs[(w * 32 + 16) * 32];
  const size_t rstep = (size_t)16 * K;

  f32x4 acc[4][4];
#pragma unroll
  for (int i = 0; i < 4; i++)
#pragma unroll
    for (int j = 0; j < 4; j++) acc[i][j] = (f32x4){0.f, 0.f, 0.f, 0.f};

  for (int k0 = 0; k0 < K; k0 += 32) {
    __syncthreads();
    gload_lds16(gA + k0, lA0);
    gload_lds16(gA + rstep + k0, lA1);
    gload_lds16(gB + k0, lB0);
    gload_lds16(gB + rstep + k0, lB1);
    __syncthreads();
    bf16x8 af[4], bfr[4];
#pragma unroll
    for (int mt = 0; mt < 4; mt++)
      af[mt] = *(const bf16x8*)&As[(wr * 64 + mt * 16 + l16) * 32 + quad * 8];
#pragma unroll
    for (int nt = 0; nt < 4; nt++)
      bfr[nt] = *(const bf16x8*)&Bs[(wc * 64 + nt * 16 + l16) * 32 + quad * 8];
#pragma unroll
    for (int mt = 0; mt < 4; mt++)
#pragma unroll
      for (int nt = 0; nt < 4; nt++)
        acc[mt][nt] = __builtin_amdgcn_mfma_f32_16x16x32_bf16(af[mt], bfr[nt], acc[mt][nt], 0, 0, 0);
  }

  float bv[4];
#pragma unroll
  for (int nt = 0; nt < 4; nt++) bv[nt] = bias[n0 + wc * 64 + nt * 16 + l16];

  if (MODE == 0) {
    float* Cout = (float*)O0;
#pragma unroll
    for (int mt = 0; mt < 4; mt++) {
      const int row = m0 + wr * 64 + mt * 16 + quad * 4;   // C/D: row = quad*4+reg
#pragma unroll
      for (int nt = 0; nt < 4; nt++) {
        const int col = n0 + wc * 64 + nt * 16 + l16;      // C/D: col = lane&15
#pragma unroll
        for (int r = 0; r < 4; r++)
          Cout[(size_t)(row + r) * N + col] = acc[mt][nt][r] + bv[nt];
      }
    }
  } else {
    const int nsec = (n0 + wc * 64) >> 10;        // 0=Q,1=K,2=V
    const int hh = ((n0 + wc * 64) >> 6) & 15;    // head
    if (nsec < 2) {
      u16* dst = (u16*)(nsec == 0 ? O0 : O1);     // [B,H,T,64]
#pragma unroll
      for (int mt = 0; mt < 4; mt++) {
        const int row = m0 + wr * 64 + mt * 16 + quad * 4;
        const int bb = row >> 11;
        const int t = row & 2047;
#pragma unroll
        for (int nt = 0; nt < 4; nt++) {
          const int dh = nt * 16 + l16;
          const size_t a = (((size_t)bb * NH + hh) * T_SZ + t) * HD + dh;
#pragma unroll
          for (int r = 0; r < 4; r++)
            dst[a + (size_t)r * HD] = f2bf(acc[mt][nt][r] + bv[nt]);
        }
      }
    } else {
      u16* vth = (u16*)O2;                        // [B,H,64,T]
#pragma unroll
      for (int mt = 0; mt < 4; mt++) {
        const int row = m0 + wr * 64 + mt * 16 + quad * 4;
        const int bb = row >> 11;
        const int t = row & 2047;
#pragma unroll
        for (int nt = 0; nt < 4; nt++) {
          const int dh = nt * 16 + l16;
          s16x4 pk;
#pragma unroll
          for (int r = 0; r < 4; r++) pk[r] = (short)f2bf(acc[mt][nt][r] + bv[nt]);
          *(s16x4*)&vth[(((size_t)bb * NH + hh) * HD + dh) * T_SZ + t] = pk;
        }
      }
    }
  }
}

// Flash attention v6 = v5 + Ps shrunk to stride-64 with 16B-chunk XOR swizzle
// (chunk c of row q stored at c^(q&7)): LDS 41984 -> 40960 B = EXACTLY
// 4 blocks/CU (was 3 + straggler -> occupancy 14%).
__launch_bounds__(256, 4)
__global__ void attn_fused(const u16* __restrict__ qh, const u16* __restrict__ kh,
                           const u16* __restrict__ vth, u16* __restrict__ out) {
  __shared__ __align__(16) u16 Ks[2][64 * 64];   // [buf][t][d] swizzled
  __shared__ __align__(16) u16 Vs[2][64 * 64];   // [buf][d][t] swizzled
  __shared__ __align__(16) u16 Ps[4][16 * 64];   // per-wave P strip, swizzled
  const int qb = 15 - blockIdx.x;                // big blocks dispatch first
  const int h = blockIdx.y, b = blockIdx.z;
  const int tid = threadIdx.x;
  const int lane = tid & 63, w = tid >> 6;
  const int quad = lane >> 4, l16 = lane & 15;
  const size_t bh = (size_t)b * NH + h;
  const u16* Kbase = kh + bh * T_SZ * HD;
  const u16* Vbase = vth + bh * HD * T_SZ;

  // DMA lane geometry: within a 1KB segment (8 rows x 128B), this lane's
  // LDS slot is (row dr, stored-chunk lane&7) -> logical chunk dc.
  const int dr = lane >> 3;                      // 0..7
  const int dc = (lane & 7) ^ dr;                // XOR swizzle
  const u16* gK0 = Kbase + (size_t)(2 * w * 8 + dr) * HD + dc * 8;
  const u16* gK1 = Kbase + (size_t)((2 * w + 1) * 8 + dr) * HD + dc * 8;
  const u16* gV0 = Vbase + (size_t)(2 * w * 8 + dr) * T_SZ + dc * 8;
  const u16* gV1 = Vbase + (size_t)((2 * w + 1) * 8 + dr) * T_SZ + dc * 8;

  // Q fragments (A-layout: m=lane&15, k=quad*8+j), pinned
  bf16x8 qf[2][2];
#pragma unroll
  for (int m = 0; m < 2; m++) {
    const int t = qb * 128 + w * 32 + m * 16 + l16;
    const u16* qrow = qh + (bh * T_SZ + t) * HD;
    qf[m][0] = *(const bf16x8*)(qrow + quad * 8);
    qf[m][1] = *(const bf16x8*)(qrow + 32 + quad * 8);
  }

  f32x4 o[2][4];
  float l_i[2][4];
#pragma unroll
  for (int m = 0; m < 2; m++)
#pragma unroll
    for (int i = 0; i < 4; i++) {
      o[m][i] = (f32x4){0.f, 0.f, 0.f, 0.f};
      l_i[m][i] = 0.f;
    }

  const int kbn = 2 * qb + 2;
  const float SC = 0.125f * LOG2E;
  // swizzled in-row element offsets for frag reads (lane-constant)
  const int sw0 = (quad ^ (l16 & 7)) * 8;        // logical chunk quad   (k 0..31)
  const int sw1 = ((4 + quad) ^ (l16 & 7)) * 8;  // logical chunk 4+quad (k 32..63)

  // prologue: stage tile 0 into buf 0
  {
    gload_lds16(gK0, &Ks[0][(2 * w) * 512]);
    gload_lds16(gK1, &Ks[0][(2 * w + 1) * 512]);
    gload_lds16(gV0, &Vs[0][(2 * w) * 512]);
    gload_lds16(gV1, &Vs[0][(2 * w + 1) * 512]);
  }

  for (int kb = 0; kb < kbn; kb++) {
    const int kt0 = kb * 64;
    __syncthreads();   // drains DMA(kb); all waves done reading buf[kb&1] from iter kb-2

    // prefetch tile kb+1 into the other buffer (hidden under this iter's compute)
    if (kb + 1 < kbn) {
      const int nb = (kb + 1) & 1;
      const size_t ko = (size_t)(kb + 1) * 64 * HD;   // K advance: 64 rows
      const int vo = (kb + 1) * 64;                    // V advance: 64 cols
      gload_lds16(gK0 + ko, &Ks[nb][(2 * w) * 512]);
      gload_lds16(gK1 + ko, &Ks[nb][(2 * w + 1) * 512]);
      gload_lds16(gV0 + vo, &Vs[nb][(2 * w) * 512]);
      gload_lds16(gV1 + vo, &Vs[nb][(2 * w + 1) * 512]);
    }

    const u16* Kb = &Ks[kb & 1][0];
    const u16* Vb = &Vs[kb & 1][0];

#pragma unroll
    for (int m = 0; m < 2; m++) {
      const int mrow = qb * 128 + w * 32 + m * 16;
      const int qr = mrow + quad * 4;
      const bool diag = (kt0 + 64 > mrow);       // wave-uniform

      // S = Q K^T (K frags read at use — swizzled addresses)
      f32x4 s[4];
#pragma unroll
      for (int nt = 0; nt < 4; nt++) {
        bf16x8 kf0 = *(const bf16x8*)&Kb[(nt * 16 + l16) * 64 + sw0];
        bf16x8 kf1 = *(const bf16x8*)&Kb[(nt * 16 + l16) * 64 + sw1];
        f32x4 t0 = (f32x4){0.f, 0.f, 0.f, 0.f};
        t0 = __builtin_amdgcn_mfma_f32_16x16x32_bf16(qf[m][0], kf0, t0, 0, 0, 0);
        t0 = __builtin_amdgcn_mfma_f32_16x16x32_bf16(qf[m][1], kf1, t0, 0, 0, 0);
        s[nt] = t0;
      }

      // p = exp2(s*SC) with causal mask; per-lane l partials
      if (diag) {
#pragma unroll
        for (int nt = 0; nt < 4; nt++) {
          const int kc = kt0 + nt * 16 + l16;
#pragma unroll
          for (int r = 0; r < 4; r++) {
            float v = (kc > qr + r) ? -10000.f : s[nt][r] * SC;
            s[nt][r] = exp2f(v);
          }
        }
      } else {
#pragma unroll
        for (int nt = 0; nt < 4; nt++)
#pragma unroll
          for (int r = 0; r < 4; r++)
            s[nt][r] = exp2f(s[nt][r] * SC);
      }
#pragma unroll
      for (int r = 0; r < 4; r++)
        l_i[m][r] += (s[0][r] + s[1][r]) + (s[2][r] + s[3][r]);

      // P: C/D -> wave-private swizzled LDS strip -> A-layout.
      // Store chunk c=t>>3 of row q at position c^(q&7); reads use sw0/sw1.
#pragma unroll
      for (int nt = 0; nt < 4; nt++) {
        const int c = nt * 2 + (l16 >> 3);       // logical 8-elem chunk of t
        const int e = l16 & 7;                   // element within chunk
#pragma unroll
        for (int r = 0; r < 4; r++) {
          const int q = quad * 4 + r;
          Ps[w][q * 64 + ((c ^ (q & 7)) * 8) + e] = f2bf_hu(s[nt][r]);
        }
      }
      bf16x8 p0 = *(const bf16x8*)&Ps[w][l16 * 64 + sw0];
      bf16x8 p1 = *(const bf16x8*)&Ps[w][l16 * 64 + sw1];
#pragma unroll
      for (int nt = 0; nt < 4; nt++) {
        bf16x8 v0 = *(const bf16x8*)&Vb[(nt * 16 + l16) * 64 + sw0];
        bf16x8 v1 = *(const bf16x8*)&Vb[(nt * 16 + l16) * 64 + sw1];
        o[m][nt] = __builtin_amdgcn_mfma_f32_16x16x32_bf16(p0, v0, o[m][nt], 0, 0, 0);
        o[m][nt] = __builtin_amdgcn_mfma_f32_16x16x32_bf16(p1, v1, o[m][nt], 0, 0, 0);
      }
    }
  }

  // epilogue: reduce l across the 16 column-lanes, normalize, write out
#pragma unroll
  for (int m = 0; m < 2; m++)
#pragma unroll
    for (int r = 0; r < 4; r++) {
      float v = l_i[m][r];
      v += __shfl_xor(v, 1);
      v += __shfl_xor(v, 2);
      v += __shfl_xor(v, 4);
      v += __shfl_xor(v, 8);
      const float inv = 1.f / v;
      const int t = qb * 128 + w * 32 + m * 16 + quad * 4 + r;
      const size_t orow = ((size_t)b * T_SZ + t) * C_SZ + (size_t)h * HD;
#pragma unroll
      for (int nt = 0; nt < 4; nt++)
        out[orow + nt * 16 + l16] = f2bf(o[m][nt][r] * inv);
    }
}

extern "C" void kernel_launch(void* const* d_in, const int* in_sizes, int n_in,
                              void* d_out, int out_size, void* d_ws, size_t ws_size,
                              hipStream_t stream) {
  (void)in_sizes; (void)n_in; (void)out_size; (void)ws_size;
  const float* x      = (const float*)d_in[0];   // [B,T,C]
  const float* W_attn = (const float*)d_in[1];   // [3C,C]
  const float* b_attn = (const float*)d_in[2];   // [3C]
  const float* W_proj = (const float*)d_in[3];   // [C,C]
  const float* b_proj = (const float*)d_in[4];   // [C]
  float* out = (float*)d_out;                    // [B,T,C] fp32

  char* ws = (char*)d_ws;
  u16* xb  = (u16*)ws;  ws += (size_t)8192 * 1024 * 2;   // 16 MB
  u16* Wab = (u16*)ws;  ws += (size_t)3072 * 1024 * 2;   //  6 MB
  u16* Wpb = (u16*)ws;  ws += (size_t)1024 * 1024 * 2;   //  2 MB
  u16* qhb = (u16*)ws;  ws += (size_t)8192 * 1024 * 2;   // 16 MB  [B,H,T,64]
  u16* khb = (u16*)ws;  ws += (size_t)8192 * 1024 * 2;   // 16 MB  [B,H,T,64]
  u16* vtb = (u16*)ws;  ws += (size_t)8192 * 1024 * 2;   // 16 MB  [B,H,64,T]
  u16* aob = (u16*)ws;                                   // 16 MB  [B,T,C]

  dim3 blk(256);
  cast_f32_bf16<<<(8192 * 1024 / 8 + 255) / 256, blk, 0, stream>>>(x, xb, 8192 * 1024 / 8);
  cast_f32_bf16<<<(3072 * 1024 / 8 + 255) / 256, blk, 0, stream>>>(W_attn, Wab, 3072 * 1024 / 8);
  cast_f32_bf16<<<(1024 * 1024 / 8 + 255) / 256, blk, 0, stream>>>(W_proj, Wpb, 1024 * 1024 / 8);

  // qkv = x @ W_attn^T + b_attn -> head-split qh/kh/vth
  gemm_bt<1><<<dim3(3072 / 128, 8192 / 128), blk, 0, stream>>>(
      xb, Wab, b_attn, qhb, khb, vtb, 8192, 3072, 1024);
  // flash attention (double-buffered DMA pipeline, 4 blocks/CU)
  attn_fused<<<dim3(16, NH, B_SZ), blk, 0, stream>>>(qhb, khb, vtb, aob);
  // y = att @ W_proj^T + b_proj (fp32 out)
  gemm_bt<0><<<dim3(1024 / 128, 8192 / 128), blk, 0, stream>>>(
      aob, Wpb, b_proj, out, nullptr, nullptr, 8192, 1024, 1024);
}

// Round 9
// 395.177 us; speedup vs baseline: 1.4381x; 1.4381x over previous
//
#include <hip/hip_runtime.h>
#include <hip/hip_bf16.h>
#include <stdint.h>

typedef unsigned short u16;
typedef __attribute__((ext_vector_type(8))) short bf16x8;   // 8 bf16 = 4 VGPRs
typedef __attribute__((ext_vector_type(4))) short s16x4;    // 4 bf16 = 8B
typedef __attribute__((ext_vector_type(4))) float f32x4;

#define B_SZ 4
#define T_SZ 2048
#define C_SZ 1024
#define NH   16
#define HD   64
#define LOG2E 1.44269504088896340736f

__device__ __forceinline__ u16 f2bf(float f) {        // RNE
  unsigned int u = __float_as_uint(f);
  u += 0x7fffu + ((u >> 16) & 1u);
  return (u16)(u >> 16);
}
__device__ __forceinline__ u16 f2bf_hu(float f) {     // round-half-up (2 ops)
  return (u16)((__float_as_uint(f) + 0x8000u) >> 16);
}
__device__ __forceinline__ void gload_lds16(const u16* g, u16* l) {
  __builtin_amdgcn_global_load_lds((const __attribute__((address_space(1))) void*)g,
                                   (__attribute__((address_space(3))) void*)l, 16, 0, 0);
}

// fp32 -> bf16 cast, 8 elements/thread
__global__ void cast_f32_bf16(const float* __restrict__ in, u16* __restrict__ out, int n8) {
  int i = blockIdx.x * blockDim.x + threadIdx.x;
  if (i < n8) {
    const float4* p = (const float4*)in + (size_t)i * 2;
    float4 a = p[0], b = p[1];
    bf16x8 o;
    o[0] = (short)f2bf(a.x); o[1] = (short)f2bf(a.y);
    o[2] = (short)f2bf(a.z); o[3] = (short)f2bf(a.w);
    o[4] = (short)f2bf(b.x); o[5] = (short)f2bf(b.y);
    o[6] = (short)f2bf(b.z); o[7] = (short)f2bf(b.w);
    ((bf16x8*)out)[i] = o;
  }
}

// C[M,N] = A[M,K](bf16) * Bw[N,K](bf16)^T + bias[N](fp32).
// MODE 0: fp32 row-major out (O0).
// MODE 1: QKV head-split epilogue: O0=qh[B,H,T,64], O1=kh[B,H,T,64], O2=vth[B,H,64,T] (bf16).
template <int MODE>
__launch_bounds__(256, 3)
__global__ void gemm_bt(const u16* __restrict__ A, const u16* __restrict__ Bw,
                        const float* __restrict__ bias,
                        void* __restrict__ O0, void* __restrict__ O1, void* __restrict__ O2,
                        int M, int N, int K) {
  __shared__ __align__(16) u16 As[128 * 32];
  __shared__ __align__(16) u16 Bs[128 * 32];
  const int tid = threadIdx.x;
  const int lane = tid & 63;
  const int w = tid >> 6;
  const int wr = w >> 1, wc = w & 1;
  const int quad = lane >> 4, l16 = lane & 15;
  const int m0 = blockIdx.y * 128;
  const int n0 = blockIdx.x * 128;

  const int srow = lane >> 2;
  const int scol = (lane & 3) * 8;
  const u16* gA = A + (size_t)(m0 + w * 32 + srow) * K + scol;
  const u16* gB = Bw + (size_t)(n0 + w * 32 + srow) * K + scol;
  u16* lA0 = &As[(w * 32) * 32];
  u16* lA1 = &As[(w * 32 + 16) * 32];
  u16* lB0 = &Bs[(w * 32) * 32];
  u16* lB1 = &Bs[(w * 32 + 16) * 32];
  const size_t rstep = (size_t)16 * K;

  f32x4 acc[4][4];
#pragma unroll
  for (int i = 0; i < 4; i++)
#pragma unroll
    for (int j = 0; j < 4; j++) acc[i][j] = (f32x4){0.f, 0.f, 0.f, 0.f};

  for (int k0 = 0; k0 < K; k0 += 32) {
    __syncthreads();
    gload_lds16(gA + k0, lA0);
    gload_lds16(gA + rstep + k0, lA1);
    gload_lds16(gB + k0, lB0);
    gload_lds16(gB + rstep + k0, lB1);
    __syncthreads();
    bf16x8 af[4], bfr[4];
#pragma unroll
    for (int mt = 0; mt < 4; mt++)
      af[mt] = *(const bf16x8*)&As[(wr * 64 + mt * 16 + l16) * 32 + quad * 8];
#pragma unroll
    for (int nt = 0; nt < 4; nt++)
      bfr[nt] = *(const bf16x8*)&Bs[(wc * 64 + nt * 16 + l16) * 32 + quad * 8];
#pragma unroll
    for (int mt = 0; mt < 4; mt++)
#pragma unroll
      for (int nt = 0; nt < 4; nt++)
        acc[mt][nt] = __builtin_amdgcn_mfma_f32_16x16x32_bf16(af[mt], bfr[nt], acc[mt][nt], 0, 0, 0);
  }

  float bv[4];
#pragma unroll
  for (int nt = 0; nt < 4; nt++) bv[nt] = bias[n0 + wc * 64 + nt * 16 + l16];

  if (MODE == 0) {
    float* Cout = (float*)O0;
#pragma unroll
    for (int mt = 0; mt < 4; mt++) {
      const int row = m0 + wr * 64 + mt * 16 + quad * 4;   // C/D: row = quad*4+reg
#pragma unroll
      for (int nt = 0; nt < 4; nt++) {
        const int col = n0 + wc * 64 + nt * 16 + l16;      // C/D: col = lane&15
#pragma unroll
        for (int r = 0; r < 4; r++)
          Cout[(size_t)(row + r) * N + col] = acc[mt][nt][r] + bv[nt];
      }
    }
  } else {
    const int nsec = (n0 + wc * 64) >> 10;        // 0=Q,1=K,2=V
    const int hh = ((n0 + wc * 64) >> 6) & 15;    // head
    if (nsec < 2) {
      u16* dst = (u16*)(nsec == 0 ? O0 : O1);     // [B,H,T,64]
#pragma unroll
      for (int mt = 0; mt < 4; mt++) {
        const int row = m0 + wr * 64 + mt * 16 + quad * 4;
        const int bb = row >> 11;
        const int t = row & 2047;
#pragma unroll
        for (int nt = 0; nt < 4; nt++) {
          const int dh = nt * 16 + l16;
          const size_t a = (((size_t)bb * NH + hh) * T_SZ + t) * HD + dh;
#pragma unroll
          for (int r = 0; r < 4; r++)
            dst[a + (size_t)r * HD] = f2bf(acc[mt][nt][r] + bv[nt]);
        }
      }
    } else {
      u16* vth = (u16*)O2;                        // [B,H,64,T]
#pragma unroll
      for (int mt = 0; mt < 4; mt++) {
        const int row = m0 + wr * 64 + mt * 16 + quad * 4;
        const int bb = row >> 11;
        const int t = row & 2047;
#pragma unroll
        for (int nt = 0; nt < 4; nt++) {
          const int dh = nt * 16 + l16;
          s16x4 pk;
#pragma unroll
          for (int r = 0; r < 4; r++) pk[r] = (short)f2bf(acc[mt][nt][r] + bv[nt]);
          *(s16x4*)&vth[(((size_t)bb * NH + hh) * HD + dh) * T_SZ + t] = pk;
        }
      }
    }
  }
}

// Flash attention v7 = v5 (round-7, 151us) + Ps at stride 64 with an
// AFFINE-IN-r swizzle: chunk c of row q stored at c ^ ((q>>2)*2).
// Store index = quad*256 + r*64 + (nt^quad)*16 + (l16>>3)*8 + (l16&7):
// r appears only as r*64 (imm offsets) — the r-dependent XOR of v6 (r8)
// triggered array->scratch demotion (197 MB spill traffic). Reads hit
// each bank exactly 8x (ideal). LDS = 40960 B -> 4 blocks/CU.
__launch_bounds__(256, 4)
__global__ void attn_fused(const u16* __restrict__ qh, const u16* __restrict__ kh,
                           const u16* __restrict__ vth, u16* __restrict__ out) {
  __shared__ __align__(16) u16 Ks[2][64 * 64];   // [buf][t][d] swizzled
  __shared__ __align__(16) u16 Vs[2][64 * 64];   // [buf][d][t] swizzled
  __shared__ __align__(16) u16 Ps[4][16 * 64];   // per-wave P strip, swizzled
  const int qb = 15 - blockIdx.x;                // big blocks dispatch first
  const int h = blockIdx.y, b = blockIdx.z;
  const int tid = threadIdx.x;
  const int lane = tid & 63, w = tid >> 6;
  const int quad = lane >> 4, l16 = lane & 15;
  const size_t bh = (size_t)b * NH + h;
  const u16* Kbase = kh + bh * T_SZ * HD;
  const u16* Vbase = vth + bh * HD * T_SZ;

  // DMA lane geometry: within a 1KB segment (8 rows x 128B), this lane's
  // LDS slot is (row dr, stored-chunk lane&7) -> logical chunk dc.
  const int dr = lane >> 3;                      // 0..7
  const int dc = (lane & 7) ^ dr;                // XOR swizzle
  const u16* gK0 = Kbase + (size_t)(2 * w * 8 + dr) * HD + dc * 8;
  const u16* gK1 = Kbase + (size_t)((2 * w + 1) * 8 + dr) * HD + dc * 8;
  const u16* gV0 = Vbase + (size_t)(2 * w * 8 + dr) * T_SZ + dc * 8;
  const u16* gV1 = Vbase + (size_t)((2 * w + 1) * 8 + dr) * T_SZ + dc * 8;

  // Q fragments (A-layout: m=lane&15, k=quad*8+j), pinned
  bf16x8 qf[2][2];
#pragma unroll
  for (int m = 0; m < 2; m++) {
    const int t = qb * 128 + w * 32 + m * 16 + l16;
    const u16* qrow = qh + (bh * T_SZ + t) * HD;
    qf[m][0] = *(const bf16x8*)(qrow + quad * 8);
    qf[m][1] = *(const bf16x8*)(qrow + 32 + quad * 8);
  }

  f32x4 o[2][4];
  float l_i[2][4];
#pragma unroll
  for (int m = 0; m < 2; m++)
#pragma unroll
    for (int i = 0; i < 4; i++) {
      o[m][i] = (f32x4){0.f, 0.f, 0.f, 0.f};
      l_i[m][i] = 0.f;
    }

  const int kbn = 2 * qb + 2;
  const float SC = 0.125f * LOG2E;
  // swizzled in-row element offsets for K/V frag reads (lane-constant)
  const int sw0 = (quad ^ (l16 & 7)) * 8;        // logical chunk quad   (k 0..31)
  const int sw1 = ((4 + quad) ^ (l16 & 7)) * 8;  // logical chunk 4+quad (k 32..63)
  // Ps read offsets (lane-constant): row l16, key = (l16>>2)*2
  const int pr0 = l16 * 64 + ((quad ^ ((l16 >> 2) * 2)) * 8);
  const int pr1 = l16 * 64 + (((4 + quad) ^ ((l16 >> 2) * 2)) * 8);
  // Ps store base (lane-constant; per-nt add (nt^quad)*16, per-r add r*64)
  const int psb = quad * 256 + ((l16 >> 3) * 8) + (l16 & 7);

  // prologue: stage tile 0 into buf 0
  {
    gload_lds16(gK0, &Ks[0][(2 * w) * 512]);
    gload_lds16(gK1, &Ks[0][(2 * w + 1) * 512]);
    gload_lds16(gV0, &Vs[0][(2 * w) * 512]);
    gload_lds16(gV1, &Vs[0][(2 * w + 1) * 512]);
  }

  for (int kb = 0; kb < kbn; kb++) {
    const int kt0 = kb * 64;
    __syncthreads();   // drains DMA(kb); all waves done reading buf[kb&1] from iter kb-2

    // prefetch tile kb+1 into the other buffer (hidden under this iter's compute)
    if (kb + 1 < kbn) {
      const int nb = (kb + 1) & 1;
      const size_t ko = (size_t)(kb + 1) * 64 * HD;   // K advance: 64 rows
      const int vo = (kb + 1) * 64;                    // V advance: 64 cols
      gload_lds16(gK0 + ko, &Ks[nb][(2 * w) * 512]);
      gload_lds16(gK1 + ko, &Ks[nb][(2 * w + 1) * 512]);
      gload_lds16(gV0 + vo, &Vs[nb][(2 * w) * 512]);
      gload_lds16(gV1 + vo, &Vs[nb][(2 * w + 1) * 512]);
    }

    const u16* Kb = &Ks[kb & 1][0];
    const u16* Vb = &Vs[kb & 1][0];

#pragma unroll
    for (int m = 0; m < 2; m++) {
      const int mrow = qb * 128 + w * 32 + m * 16;
      const int qr = mrow + quad * 4;
      const bool diag = (kt0 + 64 > mrow);       // wave-uniform

      // S = Q K^T (K frags read at use — swizzled addresses)
      f32x4 s[4];
#pragma unroll
      for (int nt = 0; nt < 4; nt++) {
        bf16x8 kf0 = *(const bf16x8*)&Kb[(nt * 16 + l16) * 64 + sw0];
        bf16x8 kf1 = *(const bf16x8*)&Kb[(nt * 16 + l16) * 64 + sw1];
        f32x4 t0 = (f32x4){0.f, 0.f, 0.f, 0.f};
        t0 = __builtin_amdgcn_mfma_f32_16x16x32_bf16(qf[m][0], kf0, t0, 0, 0, 0);
        t0 = __builtin_amdgcn_mfma_f32_16x16x32_bf16(qf[m][1], kf1, t0, 0, 0, 0);
        s[nt] = t0;
      }

      // p = exp2(s*SC) with causal mask; per-lane l partials
      if (diag) {
#pragma unroll
        for (int nt = 0; nt < 4; nt++) {
          const int kc = kt0 + nt * 16 + l16;
#pragma unroll
          for (int r = 0; r < 4; r++) {
            float v = (kc > qr + r) ? -10000.f : s[nt][r] * SC;
            s[nt][r] = exp2f(v);
          }
        }
      } else {
#pragma unroll
        for (int nt = 0; nt < 4; nt++)
#pragma unroll
          for (int r = 0; r < 4; r++)
            s[nt][r] = exp2f(s[nt][r] * SC);
      }
#pragma unroll
      for (int r = 0; r < 4; r++)
        l_i[m][r] += (s[0][r] + s[1][r]) + (s[2][r] + s[3][r]);

      // P: C/D -> wave-private swizzled LDS strip -> A-layout.
      // Affine-in-r store addressing (see kernel comment).
#pragma unroll
      for (int nt = 0; nt < 4; nt++) {
        const int a_nt = psb + ((nt ^ quad) * 16);
#pragma unroll
        for (int r = 0; r < 4; r++)
          Ps[w][a_nt + r * 64] = f2bf_hu(s[nt][r]);
      }
      bf16x8 p0 = *(const bf16x8*)&Ps[w][pr0];
      bf16x8 p1 = *(const bf16x8*)&Ps[w][pr1];
#pragma unroll
      for (int nt = 0; nt < 4; nt++) {
        bf16x8 v0 = *(const bf16x8*)&Vb[(nt * 16 + l16) * 64 + sw0];
        bf16x8 v1 = *(const bf16x8*)&Vb[(nt * 16 + l16) * 64 + sw1];
        o[m][nt] = __builtin_amdgcn_mfma_f32_16x16x32_bf16(p0, v0, o[m][nt], 0, 0, 0);
        o[m][nt] = __builtin_amdgcn_mfma_f32_16x16x32_bf16(p1, v1, o[m][nt], 0, 0, 0);
      }
    }
  }

  // epilogue: reduce l across the 16 column-lanes, normalize, write out
#pragma unroll
  for (int m = 0; m < 2; m++)
#pragma unroll
    for (int r = 0; r < 4; r++) {
      float v = l_i[m][r];
      v += __shfl_xor(v, 1);
      v += __shfl_xor(v, 2);
      v += __shfl_xor(v, 4);
      v += __shfl_xor(v, 8);
      const float inv = 1.f / v;
      const int t = qb * 128 + w * 32 + m * 16 + quad * 4 + r;
      const size_t orow = ((size_t)b * T_SZ + t) * C_SZ + (size_t)h * HD;
#pragma unroll
      for (int nt = 0; nt < 4; nt++)
        out[orow + nt * 16 + l16] = f2bf(o[m][nt][r] * inv);
    }
}

extern "C" void kernel_launch(void* const* d_in, const int* in_sizes, int n_in,
                              void* d_out, int out_size, void* d_ws, size_t ws_size,
                              hipStream_t stream) {
  (void)in_sizes; (void)n_in; (void)out_size; (void)ws_size;
  const float* x      = (const float*)d_in[0];   // [B,T,C]
  const float* W_attn = (const float*)d_in[1];   // [3C,C]
  const float* b_attn = (const float*)d_in[2];   // [3C]
  const float* W_proj = (const float*)d_in[3];   // [C,C]
  const float* b_proj = (const float*)d_in[4];   // [C]
  float* out = (float*)d_out;                    // [B,T,C] fp32

  char* ws = (char*)d_ws;
  u16* xb  = (u16*)ws;  ws += (size_t)8192 * 1024 * 2;   // 16 MB
  u16* Wab = (u16*)ws;  ws += (size_t)3072 * 1024 * 2;   //  6 MB
  u16* Wpb = (u16*)ws;  ws += (size_t)1024 * 1024 * 2;   //  2 MB
  u16* qhb = (u16*)ws;  ws += (size_t)8192 * 1024 * 2;   // 16 MB  [B,H,T,64]
  u16* khb = (u16*)ws;  ws += (size_t)8192 * 1024 * 2;   // 16 MB  [B,H,T,64]
  u16* vtb = (u16*)ws;  ws += (size_t)8192 * 1024 * 2;   // 16 MB  [B,H,64,T]
  u16* aob = (u16*)ws;                                   // 16 MB  [B,T,C]

  dim3 blk(256);
  cast_f32_bf16<<<(8192 * 1024 / 8 + 255) / 256, blk, 0, stream>>>(x, xb, 8192 * 1024 / 8);
  cast_f32_bf16<<<(3072 * 1024 / 8 + 255) / 256, blk, 0, stream>>>(W_attn, Wab, 3072 * 1024 / 8);
  cast_f32_bf16<<<(1024 * 1024 / 8 + 255) / 256, blk, 0, stream>>>(W_proj, Wpb, 1024 * 1024 / 8);

  // qkv = x @ W_attn^T + b_attn -> head-split qh/kh/vth
  gemm_bt<1><<<dim3(3072 / 128, 8192 / 128), blk, 0, stream>>>(
      xb, Wab, b_attn, qhb, khb, vtb, 8192, 3072, 1024);
  // flash attention (double-buffered DMA pipeline, 4 blocks/CU)
  attn_fused<<<dim3(16, NH, B_SZ), blk, 0, stream>>>(qhb, khb, vtb, aob);
  // y = att @ W_proj^T + b_proj (fp32 out)
  gemm_bt<0><<<dim3(1024 / 128, 8192 / 128), blk, 0, stream>>>(
      aob, Wpb, b_proj, out, nullptr, nullptr, 8192, 1024, 1024);
}

// Round 10
// 318.091 us; speedup vs baseline: 1.7867x; 1.2423x over previous
//
#include <hip/hip_runtime.h>
#include <hip/hip_bf16.h>
#include <stdint.h>

typedef unsigned short u16;
typedef __attribute__((ext_vector_type(8))) short bf16x8;   // 8 bf16 = 4 VGPRs
typedef __attribute__((ext_vector_type(4))) short s16x4;    // 4 bf16 = 8B
typedef __attribute__((ext_vector_type(4))) float f32x4;

#define B_SZ 4
#define T_SZ 2048
#define C_SZ 1024
#define NH   16
#define HD   64
#define LOG2E 1.44269504088896340736f

__device__ __forceinline__ u16 f2bf(float f) {        // RNE
  unsigned int u = __float_as_uint(f);
  u += 0x7fffu + ((u >> 16) & 1u);
  return (u16)(u >> 16);
}
__device__ __forceinline__ u16 f2bf_hu(float f) {     // round-half-up (2 ops)
  return (u16)((__float_as_uint(f) + 0x8000u) >> 16);
}
__device__ __forceinline__ void gload_lds16(const u16* g, u16* l) {
  __builtin_amdgcn_global_load_lds((const __attribute__((address_space(1))) void*)g,
                                   (__attribute__((address_space(3))) void*)l, 16, 0, 0);
}

// fp32 -> bf16 cast, 8 elements/thread
__global__ void cast_f32_bf16(const float* __restrict__ in, u16* __restrict__ out, int n8) {
  int i = blockIdx.x * blockDim.x + threadIdx.x;
  if (i < n8) {
    const float4* p = (const float4*)in + (size_t)i * 2;
    float4 a = p[0], b = p[1];
    bf16x8 o;
    o[0] = (short)f2bf(a.x); o[1] = (short)f2bf(a.y);
    o[2] = (short)f2bf(a.z); o[3] = (short)f2bf(a.w);
    o[4] = (short)f2bf(b.x); o[5] = (short)f2bf(b.y);
    o[6] = (short)f2bf(b.z); o[7] = (short)f2bf(b.w);
    ((bf16x8*)out)[i] = o;
  }
}

// C[M,N] = A[M,K](bf16) * Bw[N,K](bf16)^T + bias[N](fp32).
// MODE 0: fp32 row-major out (O0).
// MODE 1: QKV head-split epilogue: O0=qh[B,H,T,64], O1=kh[B,H,T,64], O2=vth[B,H,64,T] (bf16).
template <int MODE>
__launch_bounds__(256, 3)
__global__ void gemm_bt(const u16* __restrict__ A, const u16* __restrict__ Bw,
                        const float* __restrict__ bias,
                        void* __restrict__ O0, void* __restrict__ O1, void* __restrict__ O2,
                        int M, int N, int K) {
  __shared__ __align__(16) u16 As[128 * 32];
  __shared__ __align__(16) u16 Bs[128 * 32];
  const int tid = threadIdx.x;
  const int lane = tid & 63;
  const int w = tid >> 6;
  const int wr = w >> 1, wc = w & 1;
  const int quad = lane >> 4, l16 = lane & 15;
  const int m0 = blockIdx.y * 128;
  const int n0 = blockIdx.x * 128;

  const int srow = lane >> 2;
  const int scol = (lane & 3) * 8;
  const u16* gA = A + (size_t)(m0 + w * 32 + srow) * K + scol;
  const u16* gB = Bw + (size_t)(n0 + w * 32 + srow) * K + scol;
  u16* lA0 = &As[(w * 32) * 32];
  u16* lA1 = &As[(w * 32 + 16) * 32];
  u16* lB0 = &Bs[(w * 32) * 32];
  u16* lB1 = &Bs[(w * 32 + 16) * 32];
  const size_t rstep = (size_t)16 * K;

  f32x4 acc[4][4];
#pragma unroll
  for (int i = 0; i < 4; i++)
#pragma unroll
    for (int j = 0; j < 4; j++) acc[i][j] = (f32x4){0.f, 0.f, 0.f, 0.f};

  for (int k0 = 0; k0 < K; k0 += 32) {
    __syncthreads();
    gload_lds16(gA + k0, lA0);
    gload_lds16(gA + rstep + k0, lA1);
    gload_lds16(gB + k0, lB0);
    gload_lds16(gB + rstep + k0, lB1);
    __syncthreads();
    bf16x8 af[4], bfr[4];
#pragma unroll
    for (int mt = 0; mt < 4; mt++)
      af[mt] = *(const bf16x8*)&As[(wr * 64 + mt * 16 + l16) * 32 + quad * 8];
#pragma unroll
    for (int nt = 0; nt < 4; nt++)
      bfr[nt] = *(const bf16x8*)&Bs[(wc * 64 + nt * 16 + l16) * 32 + quad * 8];
#pragma unroll
    for (int mt = 0; mt < 4; mt++)
#pragma unroll
      for (int nt = 0; nt < 4; nt++)
        acc[mt][nt] = __builtin_amdgcn_mfma_f32_16x16x32_bf16(af[mt], bfr[nt], acc[mt][nt], 0, 0, 0);
  }

  float bv[4];
#pragma unroll
  for (int nt = 0; nt < 4; nt++) bv[nt] = bias[n0 + wc * 64 + nt * 16 + l16];

  if (MODE == 0) {
    float* Cout = (float*)O0;
#pragma unroll
    for (int mt = 0; mt < 4; mt++) {
      const int row = m0 + wr * 64 + mt * 16 + quad * 4;   // C/D: row = quad*4+reg
#pragma unroll
      for (int nt = 0; nt < 4; nt++) {
        const int col = n0 + wc * 64 + nt * 16 + l16;      // C/D: col = lane&15
#pragma unroll
        for (int r = 0; r < 4; r++)
          Cout[(size_t)(row + r) * N + col] = acc[mt][nt][r] + bv[nt];
      }
    }
  } else {
    const int nsec = (n0 + wc * 64) >> 10;        // 0=Q,1=K,2=V
    const int hh = ((n0 + wc * 64) >> 6) & 15;    // head
    if (nsec < 2) {
      u16* dst = (u16*)(nsec == 0 ? O0 : O1);     // [B,H,T,64]
#pragma unroll
      for (int mt = 0; mt < 4; mt++) {
        const int row = m0 + wr * 64 + mt * 16 + quad * 4;
        const int bb = row >> 11;
        const int t = row & 2047;
#pragma unroll
        for (int nt = 0; nt < 4; nt++) {
          const int dh = nt * 16 + l16;
          const size_t a = (((size_t)bb * NH + hh) * T_SZ + t) * HD + dh;
#pragma unroll
          for (int r = 0; r < 4; r++)
            dst[a + (size_t)r * HD] = f2bf(acc[mt][nt][r] + bv[nt]);
        }
      }
    } else {
      u16* vth = (u16*)O2;                        // [B,H,64,T]
#pragma unroll
      for (int mt = 0; mt < 4; mt++) {
        const int row = m0 + wr * 64 + mt * 16 + quad * 4;
        const int bb = row >> 11;
        const int t = row & 2047;
#pragma unroll
        for (int nt = 0; nt < 4; nt++) {
          const int dh = nt * 16 + l16;
          s16x4 pk;
#pragma unroll
          for (int r = 0; r < 4; r++) pk[r] = (short)f2bf(acc[mt][nt][r] + bv[nt]);
          *(s16x4*)&vth[(((size_t)bb * NH + hh) * HD + dh) * T_SZ + t] = pk;
        }
      }
    }
  }
}

// One k-block step of the paired flash attention. MLIM m-frags (4 = both
// q-tiles, 2 = hi tile only). r7-exact inner mechanics: stride-72 Ps with
// immediate-offset stores (NO xor with unroll vars — r8/r9 scratch demotion),
// DMA double-buffer prefetch issued right after the barrier.
template <int MLIM>
__device__ __forceinline__ void attn_step(
    int kb, int kbn_hi, int w, int quad, int l16,
    int qhi128, int qlo128, int sw0, int sw1,
    const u16* gK0, const u16* gK1, const u16* gV0, const u16* gV1,
    u16* KsF, u16* VsF, u16* PsW,
    const bf16x8 (&qf)[4][2], f32x4 (&o)[4][4], float (&l_i)[4][4]) {
  __syncthreads();   // drains DMA(kb); all waves done with buf[kb&1] from iter kb-2

  if (kb + 1 < kbn_hi) {       // prefetch tile kb+1 into the other buffer
    const int nb = (kb + 1) & 1;
    const size_t ko = (size_t)(kb + 1) * 64 * HD;   // K advance: 64 rows
    const int vo = (kb + 1) * 64;                    // V advance: 64 cols
    gload_lds16(gK0 + ko, KsF + nb * 4096 + (2 * w) * 512);
    gload_lds16(gK1 + ko, KsF + nb * 4096 + (2 * w + 1) * 512);
    gload_lds16(gV0 + vo, VsF + nb * 4096 + (2 * w) * 512);
    gload_lds16(gV1 + vo, VsF + nb * 4096 + (2 * w + 1) * 512);
  }

  const u16* Kb = KsF + (kb & 1) * 4096;
  const u16* Vb = VsF + (kb & 1) * 4096;
  const int kt0 = kb * 64;
  const float SC = 0.125f * LOG2E;

#pragma unroll
  for (int m = 0; m < MLIM; m++) {
    const int mrow = (m < 2 ? qhi128 : qlo128) + w * 32 + (m & 1) * 16;
    const int qr = mrow + quad * 4;
    const bool diag = (kt0 + 64 > mrow);       // wave-uniform

    // S = Q K^T (K frags read at use — swizzled addresses)
    f32x4 s[4];
#pragma unroll
    for (int nt = 0; nt < 4; nt++) {
      bf16x8 kf0 = *(const bf16x8*)&Kb[(nt * 16 + l16) * 64 + sw0];
      bf16x8 kf1 = *(const bf16x8*)&Kb[(nt * 16 + l16) * 64 + sw1];
      f32x4 t0 = (f32x4){0.f, 0.f, 0.f, 0.f};
      t0 = __builtin_amdgcn_mfma_f32_16x16x32_bf16(qf[m][0], kf0, t0, 0, 0, 0);
      t0 = __builtin_amdgcn_mfma_f32_16x16x32_bf16(qf[m][1], kf1, t0, 0, 0, 0);
      s[nt] = t0;
    }

    // p = exp2(s*SC) with causal mask; per-lane l partials
    if (diag) {
#pragma unroll
      for (int nt = 0; nt < 4; nt++) {
        const int kc = kt0 + nt * 16 + l16;
#pragma unroll
        for (int r = 0; r < 4; r++) {
          float v = (kc > qr + r) ? -10000.f : s[nt][r] * SC;
          s[nt][r] = exp2f(v);
        }
      }
    } else {
#pragma unroll
      for (int nt = 0; nt < 4; nt++)
#pragma unroll
        for (int r = 0; r < 4; r++)
          s[nt][r] = exp2f(s[nt][r] * SC);
    }
#pragma unroll
    for (int r = 0; r < 4; r++)
      l_i[m][r] += (s[0][r] + s[1][r]) + (s[2][r] + s[3][r]);

    // P: C/D -> wave-private LDS strip (stride 72, immediate offsets) -> A-layout
#pragma unroll
    for (int nt = 0; nt < 4; nt++)
#pragma unroll
      for (int r = 0; r < 4; r++)
        PsW[(quad * 4 + r) * 72 + nt * 16 + l16] = f2bf_hu(s[nt][r]);
    bf16x8 p0 = *(const bf16x8*)&PsW[l16 * 72 + quad * 8];
    bf16x8 p1 = *(const bf16x8*)&PsW[l16 * 72 + 32 + quad * 8];
#pragma unroll
    for (int nt = 0; nt < 4; nt++) {
      bf16x8 v0 = *(const bf16x8*)&Vb[(nt * 16 + l16) * 64 + sw0];
      bf16x8 v1 = *(const bf16x8*)&Vb[(nt * 16 + l16) * 64 + sw1];
      o[m][nt] = __builtin_amdgcn_mfma_f32_16x16x32_bf16(p0, v0, o[m][nt], 0, 0, 0);
      o[m][nt] = __builtin_amdgcn_mfma_f32_16x16x32_bf16(p1, v1, o[m][nt], 0, 0, 0);
    }
  }
}

// Flash attention v8: r7 mechanics + q-tile pairing with COMPILE-TIME m-bounds.
// Block owns tiles (qlo, qhi=15-qlo): phase 1 (kb<kbn_lo) computes 4 m-frags,
// phase 2 computes the hi tile's remaining k-blocks with 2 m-frags. Uniform
// 68 m-frag-iters/block; grid 512 = 2 blocks/CU fully resident (LDS allows 3).
// (256,2): generous VGPR cap — pairing needs ~155 live regs, do not squeeze.
__launch_bounds__(256, 2)
__global__ void attn_fused(const u16* __restrict__ qh, const u16* __restrict__ kh,
                           const u16* __restrict__ vth, u16* __restrict__ out) {
  __shared__ __align__(16) u16 Ks[2][64 * 64];   // [buf][t][d] swizzled
  __shared__ __align__(16) u16 Vs[2][64 * 64];   // [buf][d][t] swizzled
  __shared__ __align__(16) u16 Ps[4][16 * 72];   // per-wave P strip [q][t]
  const int qlo = blockIdx.x;                    // 0..7
  const int qhi = 15 - qlo;
  const int h = blockIdx.y, b = blockIdx.z;
  const int tid = threadIdx.x;
  const int lane = tid & 63, w = tid >> 6;
  const int quad = lane >> 4, l16 = lane & 15;
  const size_t bh = (size_t)b * NH + h;
  const u16* Kbase = kh + bh * T_SZ * HD;
  const u16* Vbase = vth + bh * HD * T_SZ;
  const int qhi128 = qhi * 128, qlo128 = qlo * 128;

  // DMA lane geometry (1KB segment = 8 rows x 128B): slot (dr, lane&7),
  // logical chunk dc = (lane&7)^dr  -> conflict-free swizzled tile.
  const int dr = lane >> 3;
  const int dc = (lane & 7) ^ dr;
  const u16* gK0 = Kbase + (size_t)(2 * w * 8 + dr) * HD + dc * 8;
  const u16* gK1 = Kbase + (size_t)((2 * w + 1) * 8 + dr) * HD + dc * 8;
  const u16* gV0 = Vbase + (size_t)(2 * w * 8 + dr) * T_SZ + dc * 8;
  const u16* gV1 = Vbase + (size_t)((2 * w + 1) * 8 + dr) * T_SZ + dc * 8;
  u16* KsF = &Ks[0][0];
  u16* VsF = &Vs[0][0];
  u16* PsW = &Ps[w][0];

  // Q fragments (A-layout: m=lane&15, k=quad*8+j); m 0,1 = hi tile, 2,3 = lo
  bf16x8 qf[4][2];
#pragma unroll
  for (int m = 0; m < 4; m++) {
    const int t = (m < 2 ? qhi128 : qlo128) + w * 32 + (m & 1) * 16 + l16;
    const u16* qrow = qh + (bh * T_SZ + t) * HD;
    qf[m][0] = *(const bf16x8*)(qrow + quad * 8);
    qf[m][1] = *(const bf16x8*)(qrow + 32 + quad * 8);
  }

  f32x4 o[4][4];
  float l_i[4][4];
#pragma unroll
  for (int m = 0; m < 4; m++)
#pragma unroll
    for (int i = 0; i < 4; i++) {
      o[m][i] = (f32x4){0.f, 0.f, 0.f, 0.f};
      l_i[m][i] = 0.f;
    }

  const int kbn_lo = 2 * qlo + 2;
  const int kbn_hi = 2 * qhi + 2;                // = 32 - 2*qlo > kbn_lo
  // swizzled in-row element offsets for K/V frag reads (lane-constant)
  const int sw0 = (quad ^ (l16 & 7)) * 8;
  const int sw1 = ((4 + quad) ^ (l16 & 7)) * 8;

  // prologue: stage tile 0 into buf 0
  gload_lds16(gK0, KsF + (2 * w) * 512);
  gload_lds16(gK1, KsF + (2 * w + 1) * 512);
  gload_lds16(gV0, VsF + (2 * w) * 512);
  gload_lds16(gV1, VsF + (2 * w + 1) * 512);

  // phase 1: both tiles consume k-blocks [0, kbn_lo)
  for (int kb = 0; kb < kbn_lo; kb++)
    attn_step<4>(kb, kbn_hi, w, quad, l16, qhi128, qlo128, sw0, sw1,
                 gK0, gK1, gV0, gV1, KsF, VsF, PsW, qf, o, l_i);
  // phase 2: hi tile only, k-blocks [kbn_lo, kbn_hi)
  for (int kb = kbn_lo; kb < kbn_hi; kb++)
    attn_step<2>(kb, kbn_hi, w, quad, l16, qhi128, qlo128, sw0, sw1,
                 gK0, gK1, gV0, gV1, KsF, VsF, PsW, qf, o, l_i);

  // epilogue: reduce l across the 16 column-lanes, normalize, write out
#pragma unroll
  for (int m = 0; m < 4; m++)
#pragma unroll
    for (int r = 0; r < 4; r++) {
      float v = l_i[m][r];
      v += __shfl_xor(v, 1);
      v += __shfl_xor(v, 2);
      v += __shfl_xor(v, 4);
      v += __shfl_xor(v, 8);
      const float inv = 1.f / v;
      const int t = (m < 2 ? qhi128 : qlo128) + w * 32 + (m & 1) * 16 + quad * 4 + r;
      const size_t orow = ((size_t)b * T_SZ + t) * C_SZ + (size_t)h * HD;
#pragma unroll
      for (int nt = 0; nt < 4; nt++)
        out[orow + nt * 16 + l16] = f2bf(o[m][nt][r] * inv);
    }
}

extern "C" void kernel_launch(void* const* d_in, const int* in_sizes, int n_in,
                              void* d_out, int out_size, void* d_ws, size_t ws_size,
                              hipStream_t stream) {
  (void)in_sizes; (void)n_in; (void)out_size; (void)ws_size;
  const float* x      = (const float*)d_in[0];   // [B,T,C]
  const float* W_attn = (const float*)d_in[1];   // [3C,C]
  const float* b_attn = (const float*)d_in[2];   // [3C]
  const float* W_proj = (const float*)d_in[3];   // [C,C]
  const float* b_proj = (const float*)d_in[4];   // [C]
  float* out = (float*)d_out;                    // [B,T,C] fp32

  char* ws = (char*)d_ws;
  u16* xb  = (u16*)ws;  ws += (size_t)8192 * 1024 * 2;   // 16 MB
  u16* Wab = (u16*)ws;  ws += (size_t)3072 * 1024 * 2;   //  6 MB
  u16* Wpb = (u16*)ws;  ws += (size_t)1024 * 1024 * 2;   //  2 MB
  u16* qhb = (u16*)ws;  ws += (size_t)8192 * 1024 * 2;   // 16 MB  [B,H,T,64]
  u16* khb = (u16*)ws;  ws += (size_t)8192 * 1024 * 2;   // 16 MB  [B,H,T,64]
  u16* vtb = (u16*)ws;  ws += (size_t)8192 * 1024 * 2;   // 16 MB  [B,H,64,T]
  u16* aob = (u16*)ws;                                   // 16 MB  [B,T,C]

  dim3 blk(256);
  cast_f32_bf16<<<(8192 * 1024 / 8 + 255) / 256, blk, 0, stream>>>(x, xb, 8192 * 1024 / 8);
  cast_f32_bf16<<<(3072 * 1024 / 8 + 255) / 256, blk, 0, stream>>>(W_attn, Wab, 3072 * 1024 / 8);
  cast_f32_bf16<<<(1024 * 1024 / 8 + 255) / 256, blk, 0, stream>>>(W_proj, Wpb, 1024 * 1024 / 8);

  // qkv = x @ W_attn^T + b_attn -> head-split qh/kh/vth
  gemm_bt<1><<<dim3(3072 / 128, 8192 / 128), blk, 0, stream>>>(
      xb, Wab, b_attn, qhb, khb, vtb, 8192, 3072, 1024);
  // flash attention (paired q-tiles, DMA double-buffer, 512 blocks)
  attn_fused<<<dim3(8, NH, B_SZ), blk, 0, stream>>>(qhb, khb, vtb, aob);
  // y = att @ W_proj^T + b_proj (fp32 out)
  gemm_bt<0><<<dim3(1024 / 128, 8192 / 128), blk, 0, stream>>>(
      aob, Wpb, b_proj, out, nullptr, nullptr, 8192, 1024, 1024);
}